// Round 12
// baseline (151.573 us; speedup 1.0000x reference)
//
#include <hip/hip_runtime.h>
#include <stdint.h>

// ---------------------------------------------------------------------------
// BNNLinear: out = BatchNorm( sign(x) @ sign(W)^T )
//   x: [M, K] f32, W: [N, K] f32, gamma/beta: [N] f32  ->  out: [M, N] f32
//
// Round 18 (on R17's MX-FP4 kernel, gemm ~40us, total 149.8us):
//   R17 post-mortem: FP4 matched prediction; gemm fell out of rocprof
//   top-5 (below the harness's 41us fills). Remaining slack ~14us over
//   the 15.1us MFMA + 10.5us write floor. With FP4 halving per-phase MFMA
//   cycles, the 9 barriers/tile x 16 tiles at 1 block/CU (no co-resident
//   block to absorb skew) are now the dominant slack (~6-12us).
//   Single change: REMOVE the 8 intra-tile s_barriers. Correctness holds
//   on the boundary __syncthreads alone:
//     (1) buf[cur] reads need tile-t staging done -> boundary sync drains;
//     (2) DMA into buf[nxt] vs its readers -> those ran in tile t-1, and
//         every wave passed the tile-t boundary sync since.
//   The intra-tile barriers were bf16-template scheduling structure, not
//   synchronization. Waves now free-run within a tile; compiler gets a
//   full-tile window for counted-lgkmcnt interleave. Per-phase setprio
//   kept. Everything else byte-identical to R17.
// ---------------------------------------------------------------------------

typedef int int32x4 __attribute__((ext_vector_type(4)));
typedef int int32x8 __attribute__((ext_vector_type(8)));
typedef float f32x16 __attribute__((ext_vector_type(16)));

#define BM 256
#define BN 256
#define BKI 128  // fp4 k-BYTES per LDS tile (= 256 k-elements)
#define EPS_BN 1e-5f
#define BAR_STRIDE 32  // ints between panel counters (128B, no false sharing)
#define SCALE_ONE 0x7F7F7F7F  // E8M0 exponent 127 -> 2^0 = 1.0 per block

__device__ __forceinline__ void load16_lds(const void* g, void* l) {
  // 16B per lane, LDS dest = wave-uniform base + lane*16 (linear, no scatter)
  __builtin_amdgcn_global_load_lds(
      (const __attribute__((address_space(1))) void*)g,
      (__attribute__((address_space(3))) void*)l,
      16, 0, 0);
}

__device__ __forceinline__ int32x8 mk8(int32x4 v) {
  int32x8 r = {v[0], v[1], v[2], v[3], 0, 0, 0, 0};  // fp4 uses low 4 regs
  return r;
}

// fp4 E2M1 encode of sign: +1 -> 0x2, -1 -> 0xA, 0 -> 0x0
__device__ __forceinline__ unsigned enc4(float v) {
  return v > 0.f ? 2u : (v < 0.f ? 10u : 0u);
}

// ---- 1) binarize f32 -> fp4 sign (packed 2/byte) + zero stats+barriers ----
__global__ void binarize_kernel(const float* __restrict__ x,
                                const float* __restrict__ w,
                                unsigned* __restrict__ Ab,
                                unsigned* __restrict__ Bb,
                                float* __restrict__ stats,  // colSum|colSq|bar
                                int nx8, int ntot8, int n2) {
  int idx = blockIdx.x * blockDim.x + threadIdx.x;
  if (idx < n2) stats[idx] = 0.f;  // 0.0f bit pattern == int 0
  if (idx >= ntot8) return;
  const float4* src;
  unsigned* dst;
  int i;
  if (idx < nx8) {
    src = reinterpret_cast<const float4*>(x); dst = Ab; i = idx;
  } else {
    src = reinterpret_cast<const float4*>(w); dst = Bb; i = idx - nx8;
  }
  const float4 s0 = src[2 * i];
  const float4 s1 = src[2 * i + 1];
  // element e -> nibble e (byte b = elems 2b low, 2b+1 high); same packing
  // for A and B -> any HW k-order mismatch cancels in the dot product.
  unsigned out = enc4(s0.x)        | (enc4(s0.y) << 4)  |
                 (enc4(s0.z) << 8) | (enc4(s0.w) << 12) |
                 (enc4(s1.x) << 16)| (enc4(s1.y) << 20) |
                 (enc4(s1.z) << 24)| (enc4(s1.w) << 28);
  dst[i] = out;
}

// ---- 2) fused GEMM + BatchNorm, 256^2, MX-FP4 32x32x64, barrier-light -----
// C[i][j] = sum_k sign(x)[i][k]*sign(W)[j][k] (fp4 -> f32 exact), then
// out = (C - mean_col) * gamma * rsqrt(var_col + eps) + beta, written f32.
// Two-level LDS swizzle (R16-proven, 0 conflicts): LDS row R, 16B slot c
// holds global k-chunk c ^ (R&7) ^ ((R>>3)&3); applied on the global source
// address at staging (DMA dest linear) and on the slot index at read time.
__global__ __launch_bounds__(512, 2) void gemm_bn_kernel(
    const char* __restrict__ A,    // [M][K/2] fp4-packed
    const char* __restrict__ Bt,   // [N][K/2] fp4-packed
    float* __restrict__ C,         // [M][N] f32 (final output)
    float* __restrict__ colSum,    // [N] (pre-zeroed)
    float* __restrict__ colSq,     // [N] (pre-zeroed)
    int* __restrict__ barriers,    // [16 * BAR_STRIDE] (pre-zeroed)
    const float* __restrict__ gamma,
    const float* __restrict__ beta,
    int M, int N, int K) {
  __shared__ __align__(16) char sA[2][BM * BKI];  // 2 x 32 KiB
  __shared__ __align__(16) char sB[2][BN * BKI];  // 2 x 32 KiB  (128 KiB tot)

  const int tid  = threadIdx.x;
  const int wave = tid >> 6;
  const int lane = tid & 63;
  const int Kb   = K >> 1;  // bytes per row

  // consecutive block-ids share the same B panel (L2 locality)
  const int nby = M / BM;            // row-blocks per column panel (32)
  const int panel = blockIdx.x / nby;
  const int rowBlock = (blockIdx.x % nby) * BM;
  const int colBlock = panel * BN;

  // staging: each wave stages rows [wave*32, wave*32+32) of A and of B.
  // One call = 64 lanes x 16B = 8 rows x 128B; part j covers rows j*8..j*8+7.
  const int laneRow = lane >> 3;                 // 0..7 (== LDS row & 7)
  const int cch     = lane & 7;                  // dest slot 0..7
  int swzj[4];
#pragma unroll
  for (int j = 0; j < 4; ++j) swzj[j] = ((cch ^ laneRow ^ j) & 7) * 16;

  const char* Ag = A  + (size_t)(rowBlock + wave * 32 + laneRow) * Kb;
  const char* Bg = Bt + (size_t)(colBlock + wave * 32 + laneRow) * Kb;

  const int lane31 = lane & 31;  // row (A) / col (B) within 32x32 fragment
  const int hi     = lane >> 5;  // k-half selector (16 k-bytes each)
  const int r2     = (lane31 >> 3) & 3;  // second-level swizzle bits
  const int wm = (wave >> 2) * 128;  // wave M-origin (2 waves in M)
  const int wn = (wave & 3) * 64;    // wave N-origin (4 waves in N)

  f32x16 acc[4][2] = {};  // [mi 32-row block][ni 32-col block]

  const int NT = Kb / BKI;  // 16 K-tiles (256 k-elements each)

  // prologue: stage tile 0 into buffer 0 (8 calls per wave)
#pragma unroll
  for (int j = 0; j < 4; ++j) {
    load16_lds(Ag + (size_t)(j * 8) * Kb + swzj[j],
               &sA[0][(wave * 32 + j * 8) * BKI]);
    load16_lds(Bg + (size_t)(j * 8) * Kb + swzj[j],
               &sB[0][(wave * 32 + j * 8) * BKI]);
  }

  for (int t = 0; t < NT; ++t) {
    const int cur = t & 1;
    const int nxt = cur ^ 1;
    const char* sAc = sA[cur];
    const char* sBc = sB[cur];
    const size_t gkn = (size_t)(t + 1) * BKI;
    const bool pre = (t + 1 < NT);

    // tile boundary: the ONLY barrier. Drains staging vmcnt (tile t loads
    // visible) and closes the buf[nxt] read/write race (its readers ran in
    // tile t-1; every wave has passed this sync since).
    __syncthreads();

    // B fragments for the whole tile, read ONCE (8 x ds_read_b128).
    int32x4 bfv[8];
#pragma unroll
    for (int ni = 0; ni < 2; ++ni) {
      const int row = wn + ni * 32 + lane31;
#pragma unroll
      for (int ks = 0; ks < 4; ++ks) {
        const int chunk = (((ks * 2 + hi) ^ (row & 7) ^ r2) & 7) * 16;
        bfv[ni * 4 + ks] = *reinterpret_cast<const int32x4*>(
            &sBc[row * BKI + chunk]);
      }
    }

#pragma unroll
    for (int q = 0; q < 4; ++q) {  // phase q = M-block mi (no barriers)
      // A fragments for this 32-row block (4 x ds_read_b128)
      int32x4 af[4];
      const int arow = wm + q * 32 + lane31;
#pragma unroll
      for (int ks = 0; ks < 4; ++ks) {
        const int chunk = (((ks * 2 + hi) ^ (arow & 7) ^ r2) & 7) * 16;
        af[ks] = *reinterpret_cast<const int32x4*>(&sAc[arow * BKI + chunk]);
      }

      // staging for tile t+1: 2 calls/phase (A in q0-1, B in q2-3).
      // Loads stay in flight until the next boundary syncthreads.
      if (pre) {
        if (q < 2) {
#pragma unroll
          for (int j = 0; j < 2; ++j) {
            const int part = q * 2 + j;
            load16_lds(Ag + gkn + (size_t)(part * 8) * Kb + swzj[part],
                       &sA[nxt][(wave * 32 + part * 8) * BKI]);
          }
        } else {
#pragma unroll
          for (int j = 0; j < 2; ++j) {
            const int part = (q - 2) * 2 + j;
            load16_lds(Bg + gkn + (size_t)(part * 8) * Kb + swzj[part],
                       &sB[nxt][(wave * 32 + part * 8) * BKI]);
          }
        }
      }

      __builtin_amdgcn_s_setprio(1);
#pragma unroll
      for (int ks = 0; ks < 4; ++ks)
#pragma unroll
        for (int ni = 0; ni < 2; ++ni)
          acc[q][ni] = __builtin_amdgcn_mfma_scale_f32_32x32x64_f8f6f4(
              mk8(af[ks]), mk8(bfv[ni * 4 + ks]), acc[q][ni],
              4, 4,                 // cbsz=FP4(A), blgp=FP4(B)
              0, SCALE_ONE,         // opsel_a, scale_a = 1.0
              0, SCALE_ONE);        // opsel_b, scale_b = 1.0
      __builtin_amdgcn_s_setprio(0);
    }
  }

  // ---- column stats: C/D 32x32 layout col=lane31, row=(r&3)+8(r>>2)+4hi --
#pragma unroll
  for (int ni = 0; ni < 2; ++ni) {
    const int col = colBlock + wn + ni * 32 + lane31;
    float s = 0.f, sq = 0.f;
#pragma unroll
    for (int mi = 0; mi < 4; ++mi)
#pragma unroll
      for (int r = 0; r < 16; ++r) {
        const float fv = acc[mi][ni][r];
        s += fv;
        sq += fv * fv;
      }
    // lanes l and l^32 hold the same column (different row halves)
    s  += __shfl_xor(s, 32);
    sq += __shfl_xor(sq, 32);
    if (hi == 0) {
      atomicAdd(&colSum[col], s);
      atomicAdd(&colSq[col], sq);
    }
  }

  // prefetch gamma/beta for the epilogue (latency hides under the barrier)
  float gmv = 0.f, btv = 0.f;
  if (tid < BN) {
    gmv = gamma[colBlock + tid];
    btv = beta[colBlock + tid];
  }

  // ---- per-panel grid barrier (no HW fences; R11-proven) ------------------
  // Panel p's columns touched only by its own nby row-blocks. All 256
  // blocks co-resident (128KiB LDS -> 1 block/CU x 256 CUs): no deadlock.
  __syncthreads();  // drains vmcnt: this block's stat atomics done at L3
  if (tid == 0) {
    int* bar = barriers + panel * BAR_STRIDE;
    __hip_atomic_fetch_add(bar, 1, __ATOMIC_RELAXED,
                           __HIP_MEMORY_SCOPE_AGENT);
    while (__hip_atomic_load(bar, __ATOMIC_RELAXED,
                             __HIP_MEMORY_SCOPE_AGENT) < nby) {
      __builtin_amdgcn_s_sleep(8);
    }
    asm volatile("" ::: "memory");  // compiler-only ordering; no L2 inv
  }
  __syncthreads();

  // ---- stage per-column (scale, shift) in LDS (aliased on sA) -------------
  float2* sSC = reinterpret_cast<float2*>(&sA[0][0]);  // 256 pairs = 2 KiB
  if (tid < BN) {
    const int col = colBlock + tid;
    const float s  = __hip_atomic_load(&colSum[col], __ATOMIC_RELAXED,
                                       __HIP_MEMORY_SCOPE_AGENT);
    const float sq = __hip_atomic_load(&colSq[col], __ATOMIC_RELAXED,
                                       __HIP_MEMORY_SCOPE_AGENT);
    const float invM = 1.0f / (float)M;
    const float mu  = s * invM;
    const float var = sq * invM - mu * mu;
    const float sc  = gmv * rsqrtf(var + EPS_BN);
    const float sh  = btv - mu * sc;
    sSC[tid] = make_float2(sc, sh);
  }
  __syncthreads();

  // ---- normalize in registers, write final f32 ----------------------------
#pragma unroll
  for (int ni = 0; ni < 2; ++ni) {
    const int lc  = wn + ni * 32 + lane31;  // block-local column
    const float2 ss = sSC[lc];
    const int col = colBlock + lc;
#pragma unroll
    for (int mi = 0; mi < 4; ++mi) {
#pragma unroll
      for (int r = 0; r < 16; ++r) {
        const int row = rowBlock + wm + mi * 32 + (r & 3) + 8 * (r >> 2) +
                        4 * hi;
        C[(size_t)row * N + col] = acc[mi][ni][r] * ss.x + ss.y;
      }
    }
  }
}

// ---------------------------------------------------------------------------
extern "C" void kernel_launch(void* const* d_in, const int* in_sizes, int n_in,
                              void* d_out, int out_size, void* d_ws,
                              size_t ws_size, hipStream_t stream) {
  const float* x     = (const float*)d_in[0];
  const float* w     = (const float*)d_in[1];
  const float* gamma = (const float*)d_in[2];
  const float* beta  = (const float*)d_in[3];
  float* C = (float*)d_out;

  const int N = in_sizes[2];      // OUT
  const int K = in_sizes[1] / N;  // IN
  const int M = in_sizes[0] / K;  // batch

  // workspace: [A fp4 M*K/2][B fp4 N*K/2][colSum N][colSq N][barriers]
  char* ws = (char*)d_ws;
  char* Abin = ws;
  char* Bbin = ws + (size_t)M * K / 2;
  float* stats = (float*)(ws + (size_t)M * K / 2 + (size_t)N * K / 2);
  float* colSum = stats;
  float* colSq  = stats + N;
  int* barriers = (int*)(stats + 2 * N);

  {
    int nx8 = (M * K) / 8;
    int ntot8 = (M * K + N * K) / 8;
    // zero colSum, colSq, and the 16 padded barrier counters
    binarize_kernel<<<(ntot8 + 255) / 256, 256, 0, stream>>>(
        x, w, (unsigned*)Abin, (unsigned*)Bbin, stats, nx8, ntot8,
        2 * N + 16 * BAR_STRIDE);
  }

  {
    const int nTiles = (M / BM) * (N / BN);  // 256 = 256 CUs x 1 block
    gemm_bn_kernel<<<nTiles, 512, 0, stream>>>(Abin, Bbin, C, colSum, colSq,
                                               barriers, gamma, beta, M, N, K);
  }
}